// Round 1
// baseline (444.551 us; speedup 1.0000x reference)
//
#include <hip/hip_runtime.h>
#include <math.h>

#define NH 16
#define NB 64
#define DK 64
#define NE 32768

// One block per (h, b) segment. 256 threads = 4 waves.
// Phases:
//  A: zero-fill this block's attn row [NE floats] with float4 stores
//  1: per-wave streaming of segment K rows -> dot(Q[h,b,:], K[h,e,:]) via
//     64-lane shuffle reduce; raw score -> ws[h*NE+e]; online (m,l) softmax state
//  C: cross-wave (m,l) merge in LDS
//  2: overwrite segment entries of attn row with p = exp(s-M)/L (coalesced)
//  3: per-wave streaming of segment V rows, acc[lane=d] += p * V[h,e,d];
//     cross-wave reduce in LDS -> out[h,b,:]
__global__ __launch_bounds__(256) void sdpa_seg_kernel(
    const float* __restrict__ Q,     // [NH, NB, DK]
    const float* __restrict__ K,     // [NH, NE, DK]
    const float* __restrict__ V,     // [NH, NE, DK]
    const int*   __restrict__ batch, // [NE] sorted segment ids
    float* __restrict__ out,         // [NH, NB, DK]
    float* __restrict__ attn,        // [NH, NB, NE]
    float* __restrict__ ws)          // [NH, NE] raw scores scratch
{
    const int b    = blockIdx.x;
    const int h    = blockIdx.y;
    const int tid  = threadIdx.x;
    const int wave = tid >> 6;
    const int lane = tid & 63;

    // --- segment bounds via binary search (batch sorted ascending) ---
    int lo = 0, hi = NE;
    while (lo < hi) { int mid = (lo + hi) >> 1; if (batch[mid] < b) lo = mid + 1; else hi = mid; }
    const int start = lo;
    hi = NE;
    while (lo < hi) { int mid = (lo + hi) >> 1; if (batch[mid] < b + 1) lo = mid + 1; else hi = mid; }
    const int end = lo;

    float* arow = attn + ((size_t)h * NB + b) * NE;

    // --- Phase A: zero entire attn row (segment region overwritten in phase 2) ---
    {
        float4 z4 = make_float4(0.f, 0.f, 0.f, 0.f);
        float4* arow4 = (float4*)arow;
        #pragma unroll 4
        for (int i = tid; i < NE / 4; i += 256) arow4[i] = z4;
    }

    // --- Phase 1: scores + online softmax state per wave ---
    const float qv = Q[((size_t)h * NB + b) * DK + lane];
    float* ksc = ws + (size_t)h * NE;
    float m = -INFINITY, l = 0.f;
    for (int e = start + wave; e < end; e += 4) {
        float kv = K[((size_t)h * NE + e) * DK + lane];
        float prod = qv * kv;
        #pragma unroll
        for (int off = 32; off; off >>= 1) prod += __shfl_xor(prod, off);
        if (lane == 0) ksc[e] = prod;
        float nm = fmaxf(m, prod);
        l = l * __expf(m - nm) + __expf(prod - nm);
        m = nm;
    }

    // --- Phase C: combine (m,l) across the 4 waves ---
    __shared__ float sm[4], sl[4];
    __shared__ float red[4][DK];
    if (lane == 0) { sm[wave] = m; sl[wave] = l; }
    __syncthreads();  // also orders phase A zero-writes before phase 2 p-writes,
                      // and phase 1 ws writes before phase 2/3 ws reads
    float M = fmaxf(fmaxf(sm[0], sm[1]), fmaxf(sm[2], sm[3]));
    float L = 0.f;
    #pragma unroll
    for (int w = 0; w < 4; ++w)
        L += (sl[w] > 0.f) ? sl[w] * __expf(sm[w] - M) : 0.f;
    const float inv = (L > 0.f) ? 1.f / L : 0.f;

    // --- Phase 2: write normalized probabilities into segment region ---
    for (int e = start + tid; e < end; e += 256) {
        arow[e] = __expf(ksc[e] - M) * inv;
    }

    // --- Phase 3: weighted V accumulation; lane = d component ---
    float acc = 0.f;
    for (int e = start + wave; e < end; e += 4) {
        float s = ksc[e];                       // broadcast load (same addr per wave)
        float p = __expf(s - M) * inv;
        float v = V[((size_t)h * NE + e) * DK + lane];
        acc = fmaf(p, v, acc);
    }
    red[wave][lane] = acc;
    __syncthreads();
    if (wave == 0) {
        float r = red[0][lane] + red[1][lane] + red[2][lane] + red[3][lane];
        out[((size_t)h * NB + b) * DK + lane] = r;
    }
}

extern "C" void kernel_launch(void* const* d_in, const int* in_sizes, int n_in,
                              void* d_out, int out_size, void* d_ws, size_t ws_size,
                              hipStream_t stream) {
    const float* Q     = (const float*)d_in[0];
    const float* K     = (const float*)d_in[1];
    const float* V     = (const float*)d_in[2];
    const int*   batch = (const int*)d_in[3];

    float* out  = (float*)d_out;                    // [NH,NB,DK] first
    float* attn = out + (size_t)NH * NB * DK;       // then [NH,NB,NE]
    float* ws   = (float*)d_ws;                     // [NH,NE] scores (2 MB)

    dim3 grid(NB, NH);
    sdpa_seg_kernel<<<grid, 256, 0, stream>>>(Q, K, V, batch, out, attn, ws);
}

// Round 3
// 339.458 us; speedup vs baseline: 1.3096x; 1.3096x over previous
//
#include <hip/hip_runtime.h>
#include <math.h>

#define NH 16
#define NB 64
#define DK 64
#define NE 32768
#define BLOCK 512

typedef float vf4 __attribute__((ext_vector_type(4)));  // clang vector: OK for nontemporal builtins

// ws layout: [0..127] int bounds[NB+1] (padded to 512B), then float ksc[NH*NE]
//
// Kernel 1: segment bounds from sorted batch. bounds[b] = min{e : batch[e] >= b}.
__global__ void seg_bounds_kernel(const int* __restrict__ batch, int* __restrict__ bounds) {
    int e = blockIdx.x * 256 + threadIdx.x;
    if (e >= NE) return;
    int be = batch[e];
    if (e == 0) {
        for (int b = 0; b <= be; ++b) bounds[b] = 0;
    } else {
        int bp = batch[e - 1];
        for (int b = bp + 1; b <= be; ++b) bounds[b] = e;
    }
    if (e == NE - 1) {
        for (int b = be + 1; b <= NB; ++b) bounds[b] = NE;
    }
}

// Kernel 2: one block per (h,b). 512 threads = 8 waves.
//  A: zero attn row (nontemporal 16B)
//  1: thread-per-edge dot(Q,K) via 16 independent float4 FMAs; score->ws; online (m,l)
//  R: wave shuffle-reduce (m,l), then cross-wave merge in LDS
//  2: coalesced nontemporal p-writes into segment region
//  3: wave-chunked V accumulation, lane=d, unroll 4
__global__ __launch_bounds__(BLOCK) void sdpa_seg_kernel(
    const float* __restrict__ Q,      // [NH, NB, DK]
    const float* __restrict__ K,      // [NH, NE, DK]
    const float* __restrict__ V,      // [NH, NE, DK]
    const int*   __restrict__ bounds, // [NB+1]
    float* __restrict__ out,          // [NH, NB, DK]
    float* __restrict__ attn,         // [NH, NB, NE]
    float* __restrict__ ksc_base)     // [NH, NE]
{
    const int b    = blockIdx.x;
    const int h    = blockIdx.y;
    const int tid  = threadIdx.x;
    const int wave = tid >> 6;
    const int lane = tid & 63;

    const int start = bounds[b];
    const int end   = bounds[b + 1];

    float* arow = attn + ((size_t)h * NB + b) * NE;
    float* ksc  = ksc_base + (size_t)h * NE;

    __shared__ float qs[DK];
    __shared__ float sm[8], sl[8];
    __shared__ float red[8][DK];

    if (tid < DK) qs[tid] = Q[((size_t)h * NB + b) * DK + tid];

    // --- Phase A: zero entire attn row, nontemporal (segment region overwritten later) ---
    {
        vf4 z4 = (vf4)(0.f);
        vf4* arow4 = (vf4*)arow;
        for (int i = tid; i < NE / 4; i += BLOCK)
            __builtin_nontemporal_store(z4, arow4 + i);
    }
    __syncthreads();  // qs visible

    // --- Phase 1: thread-per-edge scores; no cross-lane ops in the loop ---
    const float4* q4 = (const float4*)qs;
    float m = -INFINITY, l = 0.f;
    for (int e = start + tid; e < end; e += BLOCK) {
        const float4* kr = (const float4*)(K + ((size_t)h * NE + e) * DK);
        float sx = 0.f, sy = 0.f, sz = 0.f, sw = 0.f;
        #pragma unroll
        for (int i = 0; i < DK / 4; ++i) {
            float4 kv = kr[i];
            float4 qv = q4[i];
            sx = fmaf(kv.x, qv.x, sx);
            sy = fmaf(kv.y, qv.y, sy);
            sz = fmaf(kv.z, qv.z, sz);
            sw = fmaf(kv.w, qv.w, sw);
        }
        float s = (sx + sy) + (sz + sw);
        ksc[e] = s;
        float nm = fmaxf(m, s);
        l = l * __expf(m - nm) + __expf(s - nm);
        m = nm;
    }

    // --- wave-level (m,l) butterfly merge (once per block, not per edge) ---
    #pragma unroll
    for (int off = 32; off; off >>= 1) {
        float om = __shfl_xor(m, off);
        float ol = __shfl_xor(l, off);
        float nm = fmaxf(m, om);
        float t1 = (l  > 0.f) ? l  * __expf(m  - nm) : 0.f;
        float t2 = (ol > 0.f) ? ol * __expf(om - nm) : 0.f;
        m = nm; l = t1 + t2;
    }
    if (lane == 0) { sm[wave] = m; sl[wave] = l; }
    __syncthreads();  // also orders phase-1 ksc writes before phase-2/3 reads

    float M = -INFINITY;
    #pragma unroll
    for (int w = 0; w < 8; ++w) M = fmaxf(M, sm[w]);
    float L = 0.f;
    #pragma unroll
    for (int w = 0; w < 8; ++w) L += (sl[w] > 0.f) ? sl[w] * __expf(sm[w] - M) : 0.f;
    const float inv = (L > 0.f) ? 1.f / L : 0.f;

    // --- Phase 2: normalized p into segment region (coalesced, nontemporal) ---
    for (int e = start + tid; e < end; e += BLOCK)
        __builtin_nontemporal_store(__expf(ksc[e] - M) * inv, arow + e);

    // --- Phase 3: out[d] = sum_e p_e * V[e][d]; lane = d; contiguous chunk per wave ---
    const int S   = end - start;
    const int per = (S + 7) >> 3;
    const int cb  = start + wave * per;
    const int ce  = (cb + per < end) ? cb + per : end;

    float a0 = 0.f, a1 = 0.f, a2 = 0.f, a3 = 0.f;
    int e = cb;
    for (; e + 3 < ce; e += 4) {
        float p0 = __expf(ksc[e]     - M) * inv;
        float p1 = __expf(ksc[e + 1] - M) * inv;
        float p2 = __expf(ksc[e + 2] - M) * inv;
        float p3 = __expf(ksc[e + 3] - M) * inv;
        const float* vb = V + ((size_t)h * NE + e) * DK + lane;
        a0 = fmaf(p0, vb[0 * DK], a0);
        a1 = fmaf(p1, vb[1 * DK], a1);
        a2 = fmaf(p2, vb[2 * DK], a2);
        a3 = fmaf(p3, vb[3 * DK], a3);
    }
    for (; e < ce; ++e) {
        float p = __expf(ksc[e] - M) * inv;
        a0 = fmaf(p, V[((size_t)h * NE + e) * DK + lane], a0);
    }
    red[wave][lane] = (a0 + a1) + (a2 + a3);
    __syncthreads();
    if (wave == 0) {
        float r = 0.f;
        #pragma unroll
        for (int w = 0; w < 8; ++w) r += red[w][lane];
        out[((size_t)h * NB + b) * DK + lane] = r;
    }
}

extern "C" void kernel_launch(void* const* d_in, const int* in_sizes, int n_in,
                              void* d_out, int out_size, void* d_ws, size_t ws_size,
                              hipStream_t stream) {
    const float* Q     = (const float*)d_in[0];
    const float* K     = (const float*)d_in[1];
    const float* V     = (const float*)d_in[2];
    const int*   batch = (const int*)d_in[3];

    float* out  = (float*)d_out;                    // [NH,NB,DK]
    float* attn = out + (size_t)NH * NB * DK;       // [NH,NB,NE]

    int*   bounds = (int*)d_ws;                     // [NB+1], padded to 512 B
    float* ksc    = (float*)d_ws + 128;             // [NH,NE]

    seg_bounds_kernel<<<NE / 256, 256, 0, stream>>>(batch, bounds);

    dim3 grid(NB, NH);
    sdpa_seg_kernel<<<grid, BLOCK, 0, stream>>>(Q, K, V, bounds, out, attn, ksc);
}